// Round 14
// baseline (20485.466 us; speedup 1.0000x reference)
//
#include <hip/hip_runtime.h>
#include <math.h>

// ---------------------------------------------------------------------------
// AttentiveFP forward, MI355X. Round 6 source (resubmit x8; R6-R13 infra-failed).
// R5 lesson: streamed-global weights are latency-bound at low occupancy
// (VALUBusy 32%, Occ 17%). k_mm: 128x128 tile, BK=16 double-buffered LDS
// (40KB -> 3 blocks/CU), 8x8 thread tile (16:1 FMA:b128), stride-20 padding
// (16B-aligned b128, <=2-way conflicts = free). GRU unfused into 3 paired
// GEMMs (blockIdx.y pairs gi/gh) + elementwise gate kernels.
// ---------------------------------------------------------------------------

__device__ __forceinline__ float leaky01(float v) { return v > 0.f ? v : 0.01f * v; }
__device__ __forceinline__ float eluf(float v)    { return v > 0.f ? v : (expf(v) - 1.f); }
__device__ __forceinline__ float sigmf(float v)   { return 1.f / (1.f + expf(-v)); }

// ------------------------------ CSR build ----------------------------------

__global__ void k_hist(const int* __restrict__ idx, int* __restrict__ cnt, int n) {
  int i = blockIdx.x * 256 + threadIdx.x;
  if (i < n) atomicAdd(&cnt[idx[i]], 1);
}

__global__ void k_scan1(const int* __restrict__ in, int* __restrict__ out1,
                        int* __restrict__ bsums, int n) {
  __shared__ int s[256];
  int t = threadIdx.x;
  int i = blockIdx.x * 256 + t;
  int v = (i < n) ? in[i] : 0;
  s[t] = v;
  __syncthreads();
  for (int off = 1; off < 256; off <<= 1) {
    int tv = (t >= off) ? s[t - off] : 0;
    __syncthreads();
    s[t] += tv;
    __syncthreads();
  }
  if (i < n) out1[i] = s[t];
  if (t == 255) bsums[blockIdx.x] = s[255];
}

__global__ void k_scan2(int* __restrict__ bsums, int nb) {
  __shared__ int s[256];
  int t = threadIdx.x;
  int v = (t < nb) ? bsums[t] : 0;
  s[t] = v;
  __syncthreads();
  for (int off = 1; off < 256; off <<= 1) {
    int tv = (t >= off) ? s[t - off] : 0;
    __syncthreads();
    s[t] += tv;
    __syncthreads();
  }
  if (t < nb) bsums[t] = s[t];
}

__global__ void k_scan3(int* __restrict__ out1, const int* __restrict__ bsums, int n) {
  int b = blockIdx.x;
  if (b == 0) return;
  int i = b * 256 + threadIdx.x;
  if (i < n) out1[i] += bsums[b - 1];
}

__global__ void k_scatter(const int* __restrict__ ei, const int* __restrict__ off,
                          int* __restrict__ cur, int* __restrict__ csrc,
                          int* __restrict__ ceid, int E) {
  int e = blockIdx.x * 256 + threadIdx.x;
  if (e >= E) return;
  int s = ei[e];
  int d = ei[E + e];
  int pos = off[d] + atomicAdd(&cur[d], 1);
  csrc[pos] = s;
  ceid[pos] = e;
}

// ------------------------------ weight transpose ---------------------------

__global__ void k_tr7(const float* __restrict__ s0, const float* __restrict__ s1,
                      const float* __restrict__ s2, const float* __restrict__ s3,
                      const float* __restrict__ s4, const float* __restrict__ s5,
                      const float* __restrict__ s6, float* __restrict__ dst) {
  __shared__ float tile[128][129];
  const float* s;
  switch (blockIdx.x) {
    case 0: s = s0; break; case 1: s = s1; break; case 2: s = s2; break;
    case 3: s = s3; break; case 4: s = s4; break; case 5: s = s5; break;
    default: s = s6; break;
  }
  float* d = dst + (size_t)blockIdx.x * 16384;
  int t = threadIdx.x;
  #pragma unroll
  for (int i = 0; i < 64; ++i) {
    int idx = t + 256 * i;
    tile[idx >> 7][idx & 127] = s[idx];
  }
  __syncthreads();
  #pragma unroll
  for (int i = 0; i < 64; ++i) {
    int idx = t + 256 * i;
    d[idx] = tile[idx & 127][idx >> 7];
  }
}

// ------------------------------ k_mm: tiled GEMM ---------------------------
// C[M x 128] = act(A[M x 128] @ W[128 x 128]^T + bias), W row-major [out][k].
// 128x128 block tile, BK=16 double-buffered, 256 threads, 8x8 thread tile.
// blockIdx.y in {0,1} selects an independent (A,W,bias,C) problem (GRU gi/gh
// pairing doubles the grid for occupancy). LDS 40KB. No spill at <=168 VGPR.

#define MMACT_NONE 0
#define MMACT_LEAKY 1
#define MMACT_RELU 2
#define MMACT_ELU 3

__launch_bounds__(256, 3)
__global__ void k_mm(const float* __restrict__ A1, const float* __restrict__ W1,
                     const float* __restrict__ b1f, float* __restrict__ C1,
                     const float* __restrict__ A2, const float* __restrict__ W2,
                     const float* __restrict__ b2f, float* __restrict__ C2,
                     int M, int act) {
  __shared__ float As[2][128][20];
  __shared__ float Bs[2][128][20];
  const float* A    = blockIdx.y ? A2 : A1;
  const float* W    = blockIdx.y ? W2 : W1;
  const float* bias = blockIdx.y ? b2f : b1f;
  float*       C    = blockIdx.y ? C2 : C1;

  int t = threadIdx.x;
  int m0 = blockIdx.x * 128;
  int srow = t >> 1;              // 0..127
  int sc0  = (t & 1) * 8;         // k offset 0 or 8
  const float* arow = A + (size_t)(m0 + srow) * 128 + sc0;
  const float* wrow = W + (size_t)srow * 128 + sc0;
  bool aok = (m0 + srow) < M;
  const float4 f4z = make_float4(0.f, 0.f, 0.f, 0.f);

  // stage tile 0
  {
    float4 a0 = aok ? *(const float4*)(arow)     : f4z;
    float4 a1 = aok ? *(const float4*)(arow + 4) : f4z;
    float4 w0 = *(const float4*)(wrow);
    float4 w1 = *(const float4*)(wrow + 4);
    *(float4*)&As[0][srow][sc0]     = a0;
    *(float4*)&As[0][srow][sc0 + 4] = a1;
    *(float4*)&Bs[0][srow][sc0]     = w0;
    *(float4*)&Bs[0][srow][sc0 + 4] = w1;
  }
  __syncthreads();

  int tx = t & 15, ty = t >> 4;   // 16x16 thread grid
  float acc[8][8] = {};

  for (int kt = 0; kt < 8; ++kt) {
    int cur = kt & 1;
    float4 na0, na1, nw0, nw1;
    if (kt < 7) {                  // prefetch next tile to regs (latency hides
      int ko = (kt + 1) * 16;      // under the 1024-FMA compute below)
      na0 = aok ? *(const float4*)(arow + ko)     : f4z;
      na1 = aok ? *(const float4*)(arow + ko + 4) : f4z;
      nw0 = *(const float4*)(wrow + ko);
      nw1 = *(const float4*)(wrow + ko + 4);
    }
    #pragma unroll
    for (int k = 0; k < 16; k += 4) {
      float4 bv[8];
      #pragma unroll
      for (int j = 0; j < 8; ++j) bv[j] = *(const float4*)&Bs[cur][tx + 16 * j][k];
      #pragma unroll
      for (int i = 0; i < 8; ++i) {
        float4 av = *(const float4*)&As[cur][ty + 16 * i][k];
        #pragma unroll
        for (int j = 0; j < 8; ++j)
          acc[i][j] += av.x * bv[j].x + av.y * bv[j].y + av.z * bv[j].z + av.w * bv[j].w;
      }
    }
    if (kt < 7) {
      int nb = cur ^ 1;
      *(float4*)&As[nb][srow][sc0]     = na0;
      *(float4*)&As[nb][srow][sc0 + 4] = na1;
      *(float4*)&Bs[nb][srow][sc0]     = nw0;
      *(float4*)&Bs[nb][srow][sc0 + 4] = nw1;
    }
    __syncthreads();
  }

  #pragma unroll
  for (int i = 0; i < 8; ++i) {
    int gr = m0 + ty + 16 * i;
    if (gr >= M) continue;
    #pragma unroll
    for (int j = 0; j < 8; ++j) {
      int gc = tx + 16 * j;
      float v = acc[i][j];
      if (bias) v += bias[gc];
      if (act == MMACT_LEAKY) v = leaky01(v);
      else if (act == MMACT_RELU) v = fmaxf(v, 0.f);
      else if (act == MMACT_ELU) v = eluf(v);
      C[(size_t)gr * 128 + gc] = v;
    }
  }
}

// ------------------------------ GRU gate kernels ---------------------------

__global__ void k_sig2(const float* __restrict__ a, const float* __restrict__ b,
                       float* __restrict__ o, int n4) {
  int i = blockIdx.x * 256 + threadIdx.x;
  if (i >= n4) return;
  float4 x = ((const float4*)a)[i];
  float4 y = ((const float4*)b)[i];
  float4 r;
  r.x = sigmf(x.x + y.x); r.y = sigmf(x.y + y.y);
  r.z = sigmf(x.z + y.z); r.w = sigmf(x.w + y.w);
  ((float4*)o)[i] = r;
}

// out = relu((1-z)*tanh(gin + r*ghn) + z*h)
__global__ void k_gatefin(const float* __restrict__ gin, const float* __restrict__ ghn,
                          const float* __restrict__ R, const float* __restrict__ Z,
                          const float* __restrict__ H, float* __restrict__ out, int n4) {
  int i = blockIdx.x * 256 + threadIdx.x;
  if (i >= n4) return;
  float4 a = ((const float4*)gin)[i];
  float4 b = ((const float4*)ghn)[i];
  float4 r = ((const float4*)R)[i];
  float4 z = ((const float4*)Z)[i];
  float4 h = ((const float4*)H)[i];
  float4 o;
  o.x = fmaxf((1.f - z.x) * tanhf(a.x + r.x * b.x) + z.x * h.x, 0.f);
  o.y = fmaxf((1.f - z.y) * tanhf(a.y + r.y * b.y) + z.y * h.y, 0.f);
  o.z = fmaxf((1.f - z.z) * tanhf(a.z + r.z * b.z) + z.z * h.z, 0.f);
  o.w = fmaxf((1.f - z.w) * tanhf(a.w + r.w * b.w) + z.w * h.w, 0.f);
  ((float4*)out)[i] = o;
}

// ------------------------------ matvec (1 or 2 vectors) --------------------

__global__ void k_matvec2(const float* __restrict__ A, const float* __restrict__ v1,
                          const float* __restrict__ v2, float* __restrict__ o1,
                          float* __restrict__ o2, int M) {
  int wid = (blockIdx.x * blockDim.x + threadIdx.x) >> 6;
  int lane = threadIdx.x & 63;
  if (wid >= M) return;
  const float* a = A + (size_t)wid * 128;
  float a0 = a[lane], a1 = a[lane + 64];
  float p1 = a0 * v1[lane] + a1 * v1[lane + 64];
  #pragma unroll
  for (int o = 32; o > 0; o >>= 1) p1 += __shfl_xor(p1, o, 64);
  if (lane == 0) o1[wid] = p1;
  if (v2) {
    float p2 = a0 * v2[lane] + a1 * v2[lane + 64];
    #pragma unroll
    for (int o = 32; o > 0; o >>= 1) p2 += __shfl_xor(p2, o, 64);
    if (lane == 0) o2[wid] = p2;
  }
}

// ------------------------------ GATEConv aggregate -------------------------

__global__ void k_conv_gate(const float* __restrict__ xg, const float* __restrict__ w128,
                            const float* __restrict__ attL, const float* __restrict__ xr,
                            const float* __restrict__ ea, const int* __restrict__ off,
                            const int* __restrict__ csrc, const int* __restrict__ ceid,
                            float* __restrict__ agg, int N) {
  int wid = (blockIdx.x * blockDim.x + threadIdx.x) >> 6;
  if (wid >= N) return;
  int lane = threadIdx.x & 63;
  int j0 = lane * 2;
  float aL0 = attL[j0], aL1 = attL[j0 + 1];
  float w0 = w128[j0], w1 = w128[j0 + 1];
  float xrn = xr[wid];
  float m = -INFINITY, s = 0.f, acc0 = 0.f, acc1 = 0.f;
  int e0 = off[wid], e1 = off[wid + 1];
  for (int e = e0; e < e1; ++e) {
    int src = csrc[e];
    float eav = ea[ceid[e]];
    float2 xv = *(const float2*)(xg + (size_t)src * 128 + j0);
    float h0 = leaky01(xv.x + eav * w0);
    float h1 = leaky01(xv.y + eav * w1);
    float part = h0 * aL0 + h1 * aL1;
    #pragma unroll
    for (int o = 32; o > 0; o >>= 1) part += __shfl_xor(part, o, 64);
    float logit = leaky01(part + xrn);
    float mn = fmaxf(m, logit);
    float sc = expf(m - mn);
    float p = expf(logit - mn);
    s = s * sc + p;
    acc0 = acc0 * sc + p * h0;
    acc1 = acc1 * sc + p * h1;
    m = mn;
  }
  float r = 1.f / (s + 1e-16f);
  float2 res = make_float2(acc0 * r, acc1 * r);
  *(float2*)(agg + (size_t)wid * 128 + j0) = res;
}

// ------------------------------ GATConv ------------------------------------

__global__ void k_conv_gat(const float* __restrict__ hs, const float* __restrict__ as_,
                           const float* __restrict__ ad_, const float* __restrict__ bcl,
                           const int* __restrict__ off, const int* __restrict__ csrc,
                           float* __restrict__ hout, int N) {
  int wid = (blockIdx.x * blockDim.x + threadIdx.x) >> 6;
  if (wid >= N) return;
  int lane = threadIdx.x & 63;
  int j0 = lane * 2;
  float adn = ad_[wid];
  float m = -INFINITY, s = 0.f, acc0 = 0.f, acc1 = 0.f;
  int e0 = off[wid], e1 = off[wid + 1];
  for (int e = e0; e < e1; ++e) {
    int src = csrc[e];
    float logit = leaky01(as_[src] + adn);
    float mn = fmaxf(m, logit);
    float sc = expf(m - mn);
    float p = expf(logit - mn);
    float2 hv = *(const float2*)(hs + (size_t)src * 128 + j0);
    s = s * sc + p;
    acc0 = acc0 * sc + p * hv.x;
    acc1 = acc1 * sc + p * hv.y;
    m = mn;
  }
  float r = 1.f / (s + 1e-16f);
  hout[(size_t)wid * 128 + j0]     = eluf(acc0 * r + bcl[j0]);
  hout[(size_t)wid * 128 + j0 + 1] = eluf(acc1 * r + bcl[j0 + 1]);
}

// ------------------------------ graph pooling ------------------------------

__global__ void k_pool(const float* __restrict__ X, const int* __restrict__ goff,
                       float* __restrict__ outb, int G) {
  int wid = (blockIdx.x * blockDim.x + threadIdx.x) >> 6;
  if (wid >= G) return;
  int lane = threadIdx.x & 63;
  int j0 = lane * 2;
  float s0 = 0.f, s1 = 0.f;
  int n0 = goff[wid], n1 = goff[wid + 1];
  for (int n = n0; n < n1; ++n) {
    float2 v = *(const float2*)(X + (size_t)n * 128 + j0);
    s0 += v.x;
    s1 += v.y;
  }
  outb[(size_t)wid * 128 + j0]     = fmaxf(s0, 0.f);
  outb[(size_t)wid * 128 + j0 + 1] = fmaxf(s1, 0.f);
}

// ------------------------------ molecule conv ------------------------------

__global__ void k_conv_mol(const float* __restrict__ hsm, const float* __restrict__ asrc,
                           const float* __restrict__ adg, const float* __restrict__ bm,
                           const int* __restrict__ goff, float* __restrict__ hout, int G) {
  int wid = (blockIdx.x * blockDim.x + threadIdx.x) >> 6;
  if (wid >= G) return;
  int lane = threadIdx.x & 63;
  int j0 = lane * 2;
  float adn = adg[wid];
  float m = -INFINITY, s = 0.f, acc0 = 0.f, acc1 = 0.f;
  int n0 = goff[wid], n1 = goff[wid + 1];
  for (int n = n0; n < n1; ++n) {
    float logit = leaky01(asrc[n] + adn);
    float mn = fmaxf(m, logit);
    float sc = expf(m - mn);
    float p = expf(logit - mn);
    float2 hv = *(const float2*)(hsm + (size_t)n * 128 + j0);
    s = s * sc + p;
    acc0 = acc0 * sc + p * hv.x;
    acc1 = acc1 * sc + p * hv.y;
    m = mn;
  }
  float r = 1.f / (s + 1e-16f);
  hout[(size_t)wid * 128 + j0]     = eluf(acc0 * r + bm[j0]);
  hout[(size_t)wid * 128 + j0 + 1] = eluf(acc1 * r + bm[j0 + 1]);
}

// ------------------------------ final head ---------------------------------

__global__ void k_final(const float* __restrict__ outb, const float* __restrict__ W2,
                        const float* __restrict__ b2, const float* __restrict__ Wp1,
                        const float* __restrict__ bp1, const float* __restrict__ Wp2,
                        const float* __restrict__ bp2, float* __restrict__ y, int G) {
  int g = blockIdx.x * 256 + threadIdx.x;
  if (g >= G) return;
  const float* o = outb + (size_t)g * 128;
  float s0 = b2[0], s1 = b2[1];
  for (int k = 0; k < 128; ++k) {
    float v = o[k];
    s0 += v * W2[2 * k];
    s1 += v * W2[2 * k + 1];
  }
  float p = s0 * Wp1[0] + s1 * Wp1[1] + bp1[0];
  p = fmaxf(p, 0.f);
  y[g] = p * Wp2[0] + bp2[0];
}

// ---------------------------------------------------------------------------

extern "C" void kernel_launch(void* const* d_in, const int* in_sizes, int n_in,
                              void* d_out, int out_size, void* d_ws, size_t ws_size,
                              hipStream_t stream) {
  const int N = 50000, E = 800000, G = 1000, NL = 4;

  const float* x_in  = (const float*)d_in[0];
  const int*   ei    = (const int*)  d_in[1];
  const int*   batch = (const int*)  d_in[2];
  const float* eattr = (const float*)d_in[3];
  const float* W1    = (const float*)d_in[4];
  const float* b1    = (const float*)d_in[5];
  const float* Wg1   = (const float*)d_in[6];
  const float* attL  = (const float*)d_in[7];
  const float* attR  = (const float*)d_in[8];
  const float* Wg2   = (const float*)d_in[9];
  const float* bg    = (const float*)d_in[10];
  const float* gWi0  = (const float*)d_in[11];
  const float* gWh0  = (const float*)d_in[12];
  const float* gbi0  = (const float*)d_in[13];
  const float* gbh0  = (const float*)d_in[14];
  const float* Wc    = (const float*)d_in[15];
  const float* aS    = (const float*)d_in[16];
  const float* aD    = (const float*)d_in[17];
  const float* bc    = (const float*)d_in[18];
  const float* gWi   = (const float*)d_in[19];
  const float* gWh   = (const float*)d_in[20];
  const float* gbi   = (const float*)d_in[21];
  const float* gbh   = (const float*)d_in[22];
  const float* Wm    = (const float*)d_in[23];
  const float* aSm   = (const float*)d_in[24];
  const float* aDm   = (const float*)d_in[25];
  const float* bm    = (const float*)d_in[26];
  const float* mWi   = (const float*)d_in[27];
  const float* mWh   = (const float*)d_in[28];
  const float* mbi   = (const float*)d_in[29];
  const float* mbh   = (const float*)d_in[30];
  const float* W2    = (const float*)d_in[31];
  const float* b2    = (const float*)d_in[32];
  const float* Wp1   = (const float*)d_in[33];
  const float* bp1   = (const float*)d_in[34];
  const float* Wp2   = (const float*)d_in[35];
  const float* bp2   = (const float*)d_in[36];

  char* base = (char*)d_ws;
  size_t o = 0;
  auto alloc = [&](size_t bytes) -> char* {
    char* p = base + o;
    o += (bytes + 255) & ~(size_t)255;
    return p;
  };
  float* X    = (float*)alloc((size_t)N * 128 * 4);
  float* Hb   = (float*)alloc((size_t)N * 128 * 4);
  float* S    = (float*)alloc((size_t)N * 128 * 4);
  float* AGG  = (float*)alloc((size_t)N * 128 * 4);
  float* Nb1  = (float*)alloc((size_t)N * 128 * 4);   // GRU scratch
  float* Nb2  = (float*)alloc((size_t)N * 128 * 4);   // GRU scratch
  float* sc1  = (float*)alloc((size_t)N * 4);
  float* sc2  = (float*)alloc((size_t)N * 4);
  float* asrc = (float*)alloc((size_t)N * 4);
  float* OutB = (float*)alloc((size_t)G * 128 * 4);
  float* Hm   = (float*)alloc((size_t)G * 128 * 4);
  float* oWm  = (float*)alloc((size_t)G * 128 * 4);
  float* mB1  = (float*)alloc((size_t)G * 128 * 4);
  float* mB2  = (float*)alloc((size_t)G * 128 * 4);
  float* mB3  = (float*)alloc((size_t)G * 128 * 4);
  float* mB4  = (float*)alloc((size_t)G * 128 * 4);
  float* adg  = (float*)alloc((size_t)G * 4);
  float* WT   = (float*)alloc((size_t)7 * 16384 * 4);
  int*   deg  = (int*)alloc((size_t)N * 4);
  int*   off  = (int*)alloc((size_t)(N + 1) * 4);
  int*   cur  = (int*)alloc((size_t)N * 4);
  int*   csrc = (int*)alloc((size_t)E * 4);
  int*   ceid = (int*)alloc((size_t)E * 4);
  int*   degG = (int*)alloc((size_t)G * 4);
  int*   goff = (int*)alloc((size_t)(G + 1) * 4);
  int*   bs   = (int*)alloc(256 * 4);
  if (o > ws_size) return;  // fail visibly

  hipMemsetAsync(deg, 0, (size_t)N * 4, stream);
  hipMemsetAsync(cur, 0, (size_t)N * 4, stream);
  hipMemsetAsync(degG, 0, (size_t)G * 4, stream);
  hipMemsetAsync(off, 0, 4, stream);
  hipMemsetAsync(goff, 0, 4, stream);

  int nb1 = (N + 255) / 256;
  int nbG = (G + 255) / 256;
  k_hist<<<(E + 255) / 256, 256, 0, stream>>>(ei + E, deg, E);
  k_scan1<<<nb1, 256, 0, stream>>>(deg, off + 1, bs, N);
  k_scan2<<<1, 256, 0, stream>>>(bs, nb1);
  k_scan3<<<nb1, 256, 0, stream>>>(off + 1, bs, N);
  k_scatter<<<(E + 255) / 256, 256, 0, stream>>>(ei, off, cur, csrc, ceid, E);
  k_hist<<<(N + 255) / 256, 256, 0, stream>>>(batch, degG, N);
  k_scan1<<<nbG, 256, 0, stream>>>(degG, goff + 1, bs, G);
  k_scan2<<<1, 256, 0, stream>>>(bs, nbG);
  k_scan3<<<nbG, 256, 0, stream>>>(goff + 1, bs, G);

  // transposed weights: [0]=W1 [1]=Wg1[:128] [2]=Wg2 [3..5]=Wc [6]=Wm
  k_tr7<<<7, 256, 0, stream>>>(W1, Wg1, Wg2, Wc, Wc + 16384, Wc + 32768, Wm, WT);
  float* W1T  = WT;
  float* Wg1T = WT + 16384;
  float* Wg2T = WT + 2 * 16384;
  float* WcT  = WT + 3 * 16384;
  float* WmT  = WT + 6 * 16384;

  // single GEMM launch
  auto mm1 = [&](const float* A, const float* Wm_, const float* bias, float* C,
                 int M, int act) {
    dim3 grid((M + 127) / 128, 1);
    k_mm<<<grid, 256, 0, stream>>>(A, Wm_, bias, C, A, Wm_, bias, C, M, act);
  };
  // paired GEMM launch (two independent problems, same M)
  auto mm2 = [&](const float* A1, const float* Wa, const float* ba, float* Ca,
                 const float* A2, const float* Wb, const float* bb, float* Cb,
                 int M) {
    dim3 grid((M + 127) / 128, 2);
    k_mm<<<grid, 256, 0, stream>>>(A1, Wa, ba, Ca, A2, Wb, bb, Cb, M, MMACT_NONE);
  };
  // full GRU: out = relu(gru(inp, hid)); B1..B4 scratch [M x 128]
  auto gru = [&](const float* inp, const float* hid, const float* Wi_, const float* bi_,
                 const float* Wh_, const float* bh_, float* outp, int M,
                 float* B1, float* B2, float* B3, float* B4) {
    int n4 = M * 128 / 4;
    int gb = (n4 + 255) / 256;
    // r
    mm2(inp, Wi_,          bi_,        B1, hid, Wh_,          bh_,        B2, M);
    k_sig2<<<gb, 256, 0, stream>>>(B1, B2, B1, n4);               // R = B1
    // z
    mm2(inp, Wi_ + 16384,  bi_ + 128,  B2, hid, Wh_ + 16384,  bh_ + 128,  B3, M);
    k_sig2<<<gb, 256, 0, stream>>>(B2, B3, B2, n4);               // Z = B2
    // n parts
    mm2(inp, Wi_ + 32768,  bi_ + 256,  B3, hid, Wh_ + 32768,  bh_ + 256,  B4, M);
    k_gatefin<<<gb, 256, 0, stream>>>(B3, B4, B1, B2, hid, outp, n4);
  };

  // lin1 + leaky
  mm1(x_in, W1T, b1, X, N, MMACT_LEAKY);

  // --- GATEConv ---
  mm1(X, Wg1T, nullptr, S, N, MMACT_NONE);                      // xg = X @ Wg1[:128]
  k_matvec2<<<(N + 3) / 4, 256, 0, stream>>>(X, attR, nullptr, sc1, nullptr, N);
  k_conv_gate<<<(N + 3) / 4, 256, 0, stream>>>(S, Wg1 + 128 * 128, attL, sc1, eattr,
                                               off, csrc, ceid, AGG, N);
  mm1(AGG, Wg2T, bg, Hb, N, MMACT_ELU);                         // elu(agg@Wg2+bg)
  gru(Hb, X, gWi0, gbi0, gWh0, gbh0, X, N, S, AGG, Nb1, Nb2);

  // --- GATConv layers ---
  for (int l = 0; l < NL - 1; ++l) {
    mm1(X, WcT + (size_t)l * 16384, nullptr, S, N, MMACT_NONE); // hs
    k_matvec2<<<(N + 3) / 4, 256, 0, stream>>>(S, aS + l * 128, aD + l * 128, sc1, sc2, N);
    k_conv_gat<<<(N + 3) / 4, 256, 0, stream>>>(S, sc1, sc2, bc + l * 128, off, csrc, Hb, N);
    gru(Hb, X, gWi + (size_t)l * 384 * 128, gbi + l * 384,
        gWh + (size_t)l * 384 * 128, gbh + l * 384, X, N, S, AGG, Nb1, Nb2);
  }

  // --- molecule phase ---
  k_pool<<<(G + 3) / 4, 256, 0, stream>>>(X, goff, OutB, G);
  mm1(X, WmT, nullptr, S, N, MMACT_NONE);                       // hsm (persists both timesteps)
  k_matvec2<<<(N + 3) / 4, 256, 0, stream>>>(S, aSm, nullptr, asrc, nullptr, N);
  for (int t = 0; t < 2; ++t) {
    mm1(OutB, WmT, nullptr, oWm, G, MMACT_NONE);
    k_matvec2<<<(G + 3) / 4, 256, 0, stream>>>(oWm, aDm, nullptr, adg, nullptr, G);
    k_conv_mol<<<(G + 3) / 4, 256, 0, stream>>>(S, asrc, adg, bm, goff, Hm, G);
    gru(Hm, OutB, mWi, mbi, mWh, mbh, OutB, G, mB1, mB2, mB3, mB4);
  }

  k_final<<<(G + 255) / 256, 256, 0, stream>>>(OutB, W2, b2, Wp1, bp1, Wp2, bp2,
                                               (float*)d_out, G);
}